// Round 3
// baseline (152.127 us; speedup 1.0000x reference)
//
#include <hip/hip_runtime.h>
#include <hip/hip_bf16.h>

// Problem constants (from the JAX reference):
//   B=8, H=W=1024, N=4096 matches, R=8 -> d=17, patch=289, out (B,N,578).
// Inputs: image1/image2 float32, matches int32. Output: float32 (ref dtype).
// p1[b,n,j] = image1[b, m1 + j%17 - 8, m0 + j//17 - 8]  (zero-pad OOB)
// p2[b,n,j] = image2[b, m3 + j%17 - 8, m2 + j//17 - 8]
// normalize each 289-vector: (p - mean) / (std_ddof1 + 1e-4)

#define IMG_H 1024
#define IMG_W 1024
#define NMATCH 4096
#define DPATCH 17
#define NPATCH 289
#define RAD 8

__global__ __launch_bounds__(256) void extract_patch_kernel(
    const float* __restrict__ img1,
    const float* __restrict__ img2,
    const int* __restrict__ matches,
    float* __restrict__ out)
{
    const int tid  = blockIdx.x * blockDim.x + threadIdx.x;
    const int wave = tid >> 6;          // global wave id: 0 .. 65535
    const int lane = tid & 63;
    const int pair  = wave >> 1;        // b*4096 + n : 0 .. 32767
    const int which = wave & 1;         // 0 -> img1, 1 -> img2

    // match coords (wave-uniform scalar loads, broadcast)
    const int* m = matches + pair * 4;
    const int mx = m[which ? 2 : 0];
    const int my = m[which ? 3 : 1];

    const int b = pair >> 12;           // pair / 4096
    const float* __restrict__ imgb =
        (which ? img2 : img1) + (size_t)b * (IMG_H * IMG_W);

    // Gather 5 elements per lane: j = lane + 64k, j < 289
    float v[5];
    float sum = 0.f, sumsq = 0.f;
#pragma unroll
    for (int k = 0; k < 5; ++k) {
        const int j = lane + (k << 6);
        float val = 0.f;
        if (j < NPATCH) {
            const int iy = my + (j % DPATCH) - RAD;   // row in unpadded image
            const int ix = mx + (j / DPATCH) - RAD;   // col in unpadded image
            if ((unsigned)iy < IMG_H && (unsigned)ix < IMG_W) {
                val = imgb[iy * IMG_W + ix];
            }
        }
        v[k] = val;
        sum   += val;
        sumsq += val * val;
    }

    // wave-64 butterfly reduction
#pragma unroll
    for (int off = 32; off > 0; off >>= 1) {
        sum   += __shfl_xor(sum,   off, 64);
        sumsq += __shfl_xor(sumsq, off, 64);
    }

    const float mean = sum * (1.0f / 289.0f);
    float var = (sumsq - 289.0f * mean * mean) * (1.0f / 288.0f);
    var = fmaxf(var, 0.0f);
    const float inv = 1.0f / (sqrtf(var) + 1e-4f);

    float* __restrict__ o = out + (size_t)pair * 578 + which * NPATCH;
#pragma unroll
    for (int k = 0; k < 5; ++k) {
        const int j = lane + (k << 6);
        if (j < NPATCH) {
            o[j] = (v[k] - mean) * inv;
        }
    }
}

extern "C" void kernel_launch(void* const* d_in, const int* in_sizes, int n_in,
                              void* d_out, int out_size, void* d_ws, size_t ws_size,
                              hipStream_t stream) {
    const float* img1  = (const float*)d_in[0];
    const float* img2  = (const float*)d_in[1];
    const int* matches = (const int*)d_in[2];
    float* out         = (float*)d_out;

    // 8 * 4096 pairs * 2 images = 65536 waves; 4 waves (patches) per block
    const int n_waves = 8 * NMATCH * 2;
    dim3 block(256);
    dim3 grid(n_waves * 64 / 256);
    hipLaunchKernelGGL(extract_patch_kernel, grid, block, 0, stream,
                       img1, img2, matches, out);
}